// Round 4
// baseline (1438.716 us; speedup 1.0000x reference)
//
#include <hip/hip_runtime.h>
#include <hip/hip_fp16.h>
#include <math.h>

#define CC 512
#define HH 38
#define WW 63
#define HWSZ (HH * WW)
#define NROIS 1024
#define NP 49          // 7x7 pooled positions

// ---- LDS-tiled transpose + fp16 cast: CHW (512, 2394) f32 -> HWC (2394, 512) f16
__global__ __launch_bounds__(256) void transpose_cast(
        const float* __restrict__ src, __half* __restrict__ dst) {
    __shared__ float tile[64][65];
    int s0 = blockIdx.x * 64;
    int c0 = blockIdx.y * 64;
    int tx = threadIdx.x & 63;
    int ty = threadIdx.x >> 6;

#pragma unroll
    for (int k = 0; k < 16; ++k) {
        int c = ty * 16 + k;
        int s = s0 + tx;
        float v = (s < HWSZ) ? src[(c0 + c) * HWSZ + s] : 0.0f;
        tile[tx][c] = v;
    }
    __syncthreads();
#pragma unroll
    for (int k = 0; k < 16; ++k) {
        int s = ty * 16 + k;
        if (s0 + s < HWSZ)
            dst[(s0 + s) * CC + c0 + tx] = __float2half(tile[s][tx]);
    }
}

// ---- main kernel ------------------------------------------------------------
// Block = 256 threads = ONE roi. 4 phases x 128 channels.
// Thread t: channel cl = t&127, half ph = t>>7. ph0 computes oy 0..3, ph1
// computes oy 3..6 (row 3 overlaps; guarded stage writes keep one owner).
// Gathers: lane-consecutive channels -> 128B contiguous fp16 per wave-load.
// Stage 128ch x 49 (25 KB, stride 49 odd -> conflict-free), flush each phase's
// 25088B line-aligned chunk with dense float4 stores -> no write amplification.
__global__ __launch_bounds__(256, 4) void roi_pool_v4(
        const __half* __restrict__ img,   // HWC fp16 (2394, 512)
        const float* __restrict__ rois,   // (N, 5)
        float* __restrict__ out) {        // (N, 512, 7, 7) fp32
    __shared__ float stage[128 * NP];     // 25088 B

    int n = blockIdx.x;
    int t = threadIdx.x;
    int cl = t & 127;
    int ph = t >> 7;

    const float* r = rois + n * 5;
    float x1n = (r[1] * 0.0625f) / 62.0f;
    float y1n = (r[2] * 0.0625f) / 37.0f;
    float x2n = (r[3] * 0.0625f) / 62.0f;
    float y2n = (r[4] * 0.0625f) / 37.0f;
    float ydn = y2n - y1n;
    float xdn = x2n - x1n;

    // x-side params in registers (x1 offset derived: masked samples make the
    // exact clamp value irrelevant for invalid coords)
    float wxa[14];
    int   x0a[14];
    int   vxm = 0;
#pragma unroll
    for (int ix = 0; ix < 14; ++ix) {
        float tt = (float)ix * (1.0f / 13.0f);
        float in_x = (x1n + tt * xdn) * 62.0f;
        if (in_x >= 0.0f && in_x <= 62.0f) vxm |= (1 << ix);
        float x0f = floorf(in_x);
        wxa[ix] = in_x - x0f;
        x0a[ix] = (int)fminf(fmaxf(x0f, 0.0f), 62.0f) * CC;
    }

    for (int phase = 0; phase < 4; ++phase) {
        int c = (phase << 7) + cl;
        const __half* imgc = img + c;

#pragma unroll
        for (int oyl = 0; oyl < 4; ++oyl) {
            int oy = oyl + ph * 3;           // ph0: 0..3, ph1: 3..6
            float row[7];
#pragma unroll
            for (int ox = 0; ox < 7; ++ox) row[ox] = -INFINITY;

#pragma unroll
            for (int sy = 0; sy < 2; ++sy) {
                int iy = oy * 2 + sy;
                float tt = (float)iy * (1.0f / 13.0f);
                float in_y = (y1n + tt * ydn) * 37.0f;
                bool vy = (in_y >= 0.0f) && (in_y <= 37.0f);
                float y0f = floorf(in_y);
                float wy = in_y - y0f;
                int yy0 = (int)fminf(fmaxf(y0f, 0.0f), 37.0f);
                int yb0 = yy0 * (WW * CC);
                int yb1 = min(yb0 + WW * CC, 37 * WW * CC);

#pragma unroll
                for (int ox = 0; ox < 7; ++ox) {
#pragma unroll
                    for (int sx = 0; sx < 2; ++sx) {
                        int ix = ox * 2 + sx;
                        int xo0 = x0a[ix];
                        int xo1 = min(xo0 + CC, 62 * CC);
                        float g00 = __half2float(imgc[yb0 + xo0]);
                        float g01 = __half2float(imgc[yb0 + xo1]);
                        float g10 = __half2float(imgc[yb1 + xo0]);
                        float g11 = __half2float(imgc[yb1 + xo1]);
                        float wx = wxa[ix];
                        float top = g00 + (g01 - g00) * wx;
                        float bot = g10 + (g11 - g10) * wx;
                        float val = top + (bot - top) * wy;
                        bool valid = vy && ((vxm >> ix) & 1);
                        val = valid ? val : 0.0f;
                        row[ox] = fmaxf(row[ox], val);
                    }
                }
            }
            // guarded stage write: unique owner per output
#pragma unroll
            for (int ox = 0; ox < 7; ++ox) {
                bool mine = ph ? (oy > 3 || ox >= 4) : (oy < 3 || ox <= 3);
                if (mine) stage[cl * NP + oy * 7 + ox] = row[ox];
            }
        }
        __syncthreads();

        // flush this phase's contiguous 25088B chunk (64B-line aligned)
        const float4* s4 = (const float4*)stage;
        float4* o4 = (float4*)(out + ((n << 9) + (phase << 7)) * NP);
        for (int i = t; i < (128 * NP) / 4; i += 256)   // 1568 float4
            o4[i] = s4[i];
        __syncthreads();
    }
}

// ---- fallback (ws too small): direct CHW fp32 gathers, LDS-staged stores ----
__global__ __launch_bounds__(256) void roi_pool_chw(
        const float* __restrict__ img,
        const float* __restrict__ rois,
        float* __restrict__ out) {
    __shared__ float stage[256 * NP];
    int n = blockIdx.x >> 1;
    int h = blockIdx.x & 1;
    int t = threadIdx.x;
    int c = (h << 8) + t;

    const float* r = rois + n * 5;
    float x1n = (r[1] * 0.0625f) / 62.0f;
    float y1n = (r[2] * 0.0625f) / 37.0f;
    float x2n = (r[3] * 0.0625f) / 62.0f;
    float y2n = (r[4] * 0.0625f) / 37.0f;
    float ydn = y2n - y1n;
    float xdn = x2n - x1n;

    const float* imgc = img + c * HWSZ;

    float wxa[14];
    int   x0a[14], x1a[14];
    int   vxm = 0;
#pragma unroll
    for (int ix = 0; ix < 14; ++ix) {
        float tt = (float)ix * (1.0f / 13.0f);
        float in_x = (x1n + tt * xdn) * 62.0f;
        if (in_x >= 0.0f && in_x <= 62.0f) vxm |= (1 << ix);
        float x0f = floorf(in_x);
        wxa[ix] = in_x - x0f;
        x0a[ix] = (int)fminf(fmaxf(x0f, 0.0f), 62.0f);
        x1a[ix] = (int)fminf(fmaxf(x0f + 1.0f, 0.0f), 62.0f);
    }

#pragma unroll
    for (int oy = 0; oy < 7; ++oy) {
        float row[7];
#pragma unroll
        for (int ox = 0; ox < 7; ++ox) row[ox] = -INFINITY;
#pragma unroll
        for (int sy = 0; sy < 2; ++sy) {
            int iy = oy * 2 + sy;
            float tt = (float)iy * (1.0f / 13.0f);
            float in_y = (y1n + tt * ydn) * 37.0f;
            bool vy = (in_y >= 0.0f) && (in_y <= 37.0f);
            float y0f = floorf(in_y);
            float wy = in_y - y0f;
            int yy0 = (int)fminf(fmaxf(y0f, 0.0f), 37.0f);
            int yy1 = (int)fminf(fmaxf(y0f + 1.0f, 0.0f), 37.0f);
            int yb0 = yy0 * WW;
            int yb1 = yy1 * WW;
#pragma unroll
            for (int ox = 0; ox < 7; ++ox) {
#pragma unroll
                for (int sx = 0; sx < 2; ++sx) {
                    int ix = ox * 2 + sx;
                    float g00 = imgc[yb0 + x0a[ix]];
                    float g01 = imgc[yb0 + x1a[ix]];
                    float g10 = imgc[yb1 + x0a[ix]];
                    float g11 = imgc[yb1 + x1a[ix]];
                    float wx = wxa[ix];
                    float top = g00 + (g01 - g00) * wx;
                    float bot = g10 + (g11 - g10) * wx;
                    float val = top + (bot - top) * wy;
                    bool valid = vy && ((vxm >> ix) & 1);
                    val = valid ? val : 0.0f;
                    row[ox] = fmaxf(row[ox], val);
                }
            }
        }
#pragma unroll
        for (int ox = 0; ox < 7; ++ox)
            stage[t * NP + oy * 7 + ox] = row[ox];
    }

    __syncthreads();
    const float4* s4 = (const float4*)stage;
    float4* o4 = (float4*)(out + ((n << 9) + (h << 8)) * NP);
    for (int i = t; i < (256 * NP) / 4; i += 256)
        o4[i] = s4[i];
}

extern "C" void kernel_launch(void* const* d_in, const int* in_sizes, int n_in,
                              void* d_out, int out_size, void* d_ws, size_t ws_size,
                              hipStream_t stream) {
    const float* bottom = (const float*)d_in[0];
    const float* rois   = (const float*)d_in[1];
    float* out = (float*)d_out;

    const size_t need = (size_t)CC * HWSZ * sizeof(__half);  // ~2.45 MB
    if (ws_size >= need) {
        __half* img = (__half*)d_ws;
        dim3 tg((HWSZ + 63) / 64, CC / 64);   // 38 x 8
        transpose_cast<<<tg, 256, 0, stream>>>(bottom, img);
        roi_pool_v4<<<NROIS, 256, 0, stream>>>(img, rois, out);
    } else {
        roi_pool_chw<<<NROIS * 2, 256, 0, stream>>>(bottom, rois, out);
    }
}

// Round 5
// 178.459 us; speedup vs baseline: 8.0619x; 8.0619x over previous
//
#include <hip/hip_runtime.h>
#include <math.h>

#define CC 512
#define HH 38
#define WW 63
#define HWSZ (HH * WW)
#define NROIS 1024
#define NP 49          // 7x7 pooled positions

// ---------------- LDS-tiled transpose: CHW (512, 2394) -> HWC (2394, 512) ----
__global__ __launch_bounds__(256) void transpose_tiled(
        const float* __restrict__ src, float* __restrict__ dst) {
    __shared__ float tile[64][65];
    int s0 = blockIdx.x * 64;
    int c0 = blockIdx.y * 64;
    int tx = threadIdx.x & 63;
    int ty = threadIdx.x >> 6;

#pragma unroll
    for (int k = 0; k < 16; ++k) {
        int c = ty * 16 + k;
        int s = s0 + tx;
        float v = (s < HWSZ) ? src[(c0 + c) * HWSZ + s] : 0.0f;
        tile[tx][c] = v;
    }
    __syncthreads();
#pragma unroll
    for (int k = 0; k < 16; ++k) {
        int s = ty * 16 + k;
        if (s0 + s < HWSZ)
            dst[(s0 + s) * CC + c0 + tx] = tile[s][tx];
    }
}

// ---------------- main kernel ------------------------------------------------
// Block = 256 threads = QUARTER roi (128 channels). Thread t: channel
// cl = t&127 of this quarter; ph = t>>7 splits the 7 output rows disjointly
// (ph0: oy 0..3 / iy 0..7, ph1: oy 4..6 / iy 8..13 -> no duplicated samples;
// ph is wave-uniform -> no divergence). Gathers stay lane-fastest-in-c
// (coalesced 256B/wave). Stage = 128ch x 49 f32 (25088 B, stride 49 odd ->
// conflict-free; 6 blocks/CU by LDS -> ~24 waves/CU). Flush: the quarter-roi
// region is contiguous + line-aligned in global -> dense float4 stores, no
// write amplification. NO __launch_bounds__ min-waves: let the compiler keep
// all arrays in registers (v4's clamp caused catastrophic spill traffic).
__global__ __launch_bounds__(256) void roi_pool_v5(
        const float* __restrict__ img,    // HWC (2394, 512)
        const float* __restrict__ rois,   // (N, 5)
        float* __restrict__ out) {        // (N, 512, 7, 7)
    __shared__ float stage[128 * NP];     // 25088 B

    int n = blockIdx.x >> 2;              // wave-uniform
    int q = blockIdx.x & 3;
    int t = threadIdx.x;
    int cl = t & 127;
    int ph = t >> 7;                      // wave-uniform (waves 0,1 vs 2,3)
    int c = (q << 7) + cl;

    const float* r = rois + n * 5;
    float x1n = (r[1] * 0.0625f) / 62.0f;
    float y1n = (r[2] * 0.0625f) / 37.0f;
    float x2n = (r[3] * 0.0625f) / 62.0f;
    float y2n = (r[4] * 0.0625f) / 37.0f;
    float ydn = y2n - y1n;
    float xdn = x2n - x1n;

    const float* imgc = img + c;

    // x-side interpolation params (fully unrolled -> registers)
    float wxa[14];
    int   x0a[14], x1a[14];
    int   vxm = 0;
#pragma unroll
    for (int ix = 0; ix < 14; ++ix) {
        float tt = (float)ix * (1.0f / 13.0f);
        float in_x = (x1n + tt * xdn) * 62.0f;
        if (in_x >= 0.0f && in_x <= 62.0f) vxm |= (1 << ix);
        float x0f = floorf(in_x);
        wxa[ix] = in_x - x0f;
        x0a[ix] = (int)fminf(fmaxf(x0f, 0.0f), 62.0f) * CC;
        x1a[ix] = (int)fminf(fmaxf(x0f + 1.0f, 0.0f), 62.0f) * CC;
    }

    auto do_row = [&](int oy) {
        float row[7];
#pragma unroll
        for (int ox = 0; ox < 7; ++ox) row[ox] = -INFINITY;

#pragma unroll
        for (int sy = 0; sy < 2; ++sy) {
            int iy = oy * 2 + sy;
            float tt = (float)iy * (1.0f / 13.0f);
            float in_y = (y1n + tt * ydn) * 37.0f;
            bool vy = (in_y >= 0.0f) && (in_y <= 37.0f);
            float y0f = floorf(in_y);
            float wy = in_y - y0f;
            int yy0 = (int)fminf(fmaxf(y0f, 0.0f), 37.0f);
            int yy1 = (int)fminf(fmaxf(y0f + 1.0f, 0.0f), 37.0f);
            int yb0 = yy0 * (WW * CC);
            int yb1 = yy1 * (WW * CC);

#pragma unroll
            for (int ox = 0; ox < 7; ++ox) {
#pragma unroll
                for (int sx = 0; sx < 2; ++sx) {
                    int ix = ox * 2 + sx;
                    float g00 = imgc[yb0 + x0a[ix]];
                    float g01 = imgc[yb0 + x1a[ix]];
                    float g10 = imgc[yb1 + x0a[ix]];
                    float g11 = imgc[yb1 + x1a[ix]];
                    float wx = wxa[ix];
                    float top = g00 + (g01 - g00) * wx;
                    float bot = g10 + (g11 - g10) * wx;
                    float val = top + (bot - top) * wy;
                    bool valid = vy && ((vxm >> ix) & 1);
                    val = valid ? val : 0.0f;
                    row[ox] = fmaxf(row[ox], val);
                }
            }
        }
#pragma unroll
        for (int ox = 0; ox < 7; ++ox)
            stage[cl * NP + oy * 7 + ox] = row[ox];  // stride 49: conflict-free
    };

    if (ph == 0) {
#pragma unroll
        for (int oy = 0; oy < 4; ++oy) do_row(oy);
    } else {
#pragma unroll
        for (int oy = 4; oy < 7; ++oy) do_row(oy);
    }

    __syncthreads();

    // dense coalesced store of the contiguous quarter-roi region (25088 B)
    const float4* s4 = (const float4*)stage;
    float4* o4 = (float4*)(out + ((n << 9) + (q << 7)) * NP);
    for (int i = t; i < (128 * NP) / 4; i += 256)    // 1568 float4
        o4[i] = s4[i];
}

// ---------------- fallback (ws too small): direct CHW gathers ----------------
__global__ __launch_bounds__(256) void roi_pool_chw(
        const float* __restrict__ img,    // CHW
        const float* __restrict__ rois,
        float* __restrict__ out) {
    __shared__ float stage[256 * NP];
    int n = blockIdx.x >> 1;
    int h = blockIdx.x & 1;
    int t = threadIdx.x;
    int c = (h << 8) + t;

    const float* r = rois + n * 5;
    float x1n = (r[1] * 0.0625f) / 62.0f;
    float y1n = (r[2] * 0.0625f) / 37.0f;
    float x2n = (r[3] * 0.0625f) / 62.0f;
    float y2n = (r[4] * 0.0625f) / 37.0f;
    float ydn = y2n - y1n;
    float xdn = x2n - x1n;

    const float* imgc = img + c * HWSZ;

    float wxa[14];
    int   x0a[14], x1a[14];
    int   vxm = 0;
#pragma unroll
    for (int ix = 0; ix < 14; ++ix) {
        float tt = (float)ix * (1.0f / 13.0f);
        float in_x = (x1n + tt * xdn) * 62.0f;
        if (in_x >= 0.0f && in_x <= 62.0f) vxm |= (1 << ix);
        float x0f = floorf(in_x);
        wxa[ix] = in_x - x0f;
        x0a[ix] = (int)fminf(fmaxf(x0f, 0.0f), 62.0f);
        x1a[ix] = (int)fminf(fmaxf(x0f + 1.0f, 0.0f), 62.0f);
    }

#pragma unroll
    for (int oy = 0; oy < 7; ++oy) {
        float row[7];
#pragma unroll
        for (int ox = 0; ox < 7; ++ox) row[ox] = -INFINITY;
#pragma unroll
        for (int sy = 0; sy < 2; ++sy) {
            int iy = oy * 2 + sy;
            float tt = (float)iy * (1.0f / 13.0f);
            float in_y = (y1n + tt * ydn) * 37.0f;
            bool vy = (in_y >= 0.0f) && (in_y <= 37.0f);
            float y0f = floorf(in_y);
            float wy = in_y - y0f;
            int yy0 = (int)fminf(fmaxf(y0f, 0.0f), 37.0f);
            int yy1 = (int)fminf(fmaxf(y0f + 1.0f, 0.0f), 37.0f);
            int yb0 = yy0 * WW;
            int yb1 = yy1 * WW;
#pragma unroll
            for (int ox = 0; ox < 7; ++ox) {
#pragma unroll
                for (int sx = 0; sx < 2; ++sx) {
                    int ix = ox * 2 + sx;
                    float g00 = imgc[yb0 + x0a[ix]];
                    float g01 = imgc[yb0 + x1a[ix]];
                    float g10 = imgc[yb1 + x0a[ix]];
                    float g11 = imgc[yb1 + x1a[ix]];
                    float wx = wxa[ix];
                    float top = g00 + (g01 - g00) * wx;
                    float bot = g10 + (g11 - g10) * wx;
                    float val = top + (bot - top) * wy;
                    bool valid = vy && ((vxm >> ix) & 1);
                    val = valid ? val : 0.0f;
                    row[ox] = fmaxf(row[ox], val);
                }
            }
        }
#pragma unroll
        for (int ox = 0; ox < 7; ++ox)
            stage[t * NP + oy * 7 + ox] = row[ox];
    }

    __syncthreads();
    const float4* s4 = (const float4*)stage;
    float4* o4 = (float4*)(out + ((n << 9) + (h << 8)) * NP);
    for (int i = t; i < (256 * NP) / 4; i += 256)
        o4[i] = s4[i];
}

extern "C" void kernel_launch(void* const* d_in, const int* in_sizes, int n_in,
                              void* d_out, int out_size, void* d_ws, size_t ws_size,
                              hipStream_t stream) {
    const float* bottom = (const float*)d_in[0];
    const float* rois   = (const float*)d_in[1];
    float* out = (float*)d_out;

    const size_t need = (size_t)CC * HWSZ * sizeof(float);  // ~4.9 MB
    if (ws_size >= need) {
        float* img = (float*)d_ws;
        dim3 tg((HWSZ + 63) / 64, CC / 64);   // 38 x 8
        transpose_tiled<<<tg, 256, 0, stream>>>(bottom, img);
        roi_pool_v5<<<NROIS * 4, 256, 0, stream>>>(img, rois, out);
    } else {
        roi_pool_chw<<<NROIS * 2, 256, 0, stream>>>(bottom, rois, out);
    }
}